// Round 5
// baseline (559.720 us; speedup 1.0000x reference)
//
#include <hip/hip_runtime.h>

typedef unsigned short u16;
typedef __attribute__((ext_vector_type(8))) short bf16x8;
typedef __attribute__((ext_vector_type(4))) float f32x4;

struct __align__(8) u16x4_t { u16 x, y, z, w; };

__device__ __forceinline__ float b2f(u16 b) {
  union { unsigned u; float f; } v; v.u = ((unsigned)b) << 16; return v.f;
}
__device__ __forceinline__ u16 f2b(float f) {
  union { float f; unsigned u; } v; v.f = f;
  unsigned r = v.u + 0x7fffu + ((v.u >> 16) & 1u);
  return (u16)(r >> 16);
}
// pack two f32 -> bf16x2 (round half-up): 2 adds + 1 v_perm
__device__ __forceinline__ unsigned pk2(float x, float y) {
  union { float f; unsigned u; } a, b; a.f = x; b.f = y;
  return __builtin_amdgcn_perm(b.u + 0x8000u, a.u + 0x8000u, 0x07060302u);
}
__device__ __forceinline__ bf16x8 pack8(float4 lo, float4 hi) {
  union { bf16x8 v; unsigned u[4]; } t;
  t.u[0] = pk2(lo.x, lo.y); t.u[1] = pk2(lo.z, lo.w);
  t.u[2] = pk2(hi.x, hi.y); t.u[3] = pk2(hi.z, hi.w);
  return t.v;
}

// ---------------- fused: weight cvt (blocks 0..447) + mask/mlist build (448..545) ----------------
__global__ void init_misc(const float* __restrict__ Wp, const float* __restrict__ Wi,
                          const float* __restrict__ Wh, u16* __restrict__ wb,
                          const int* __restrict__ main_idx, int* __restrict__ mask,
                          int* __restrict__ mlist, int* __restrict__ cpos,
                          int* __restrict__ mcount, int nMain) {
  int b = blockIdx.x;
  if (b < 448) {
    int t = b * 256 + threadIdx.x;      // [0, 114688)
    const float* src; int o;
    if (t < 16384)      { src = Wp; o = t; }
    else if (t < 65536) { src = Wi; o = t - 16384; }
    else                { src = Wh; o = t - 65536; }
    float4 v = ((const float4*)src)[o];
    u16x4_t q;
    q.x = f2b(v.x); q.y = f2b(v.y); q.z = f2b(v.z); q.w = f2b(v.w);
    ((u16x4_t*)wb)[t] = q;
  } else {
    int t = (b - 448) * 256 + threadIdx.x;
    if (t < nMain) {
      int o = main_idx[t];
      if (atomicCAS(&mask[o], 0, 1) == 0) {
        int i = atomicAdd(mcount, 1);
        mlist[i] = o;
        cpos[o] = i;
      }
    }
  }
}

// ---------------- masked degree count ----------------
__global__ void count_edges(const int* __restrict__ obj_idx, const int* __restrict__ mask,
                            int* __restrict__ deg, int n) {
  int e = blockIdx.x * 256 + threadIdx.x;
  if (e >= n) return;
  int o = obj_idx[e];
  if (mask[o]) atomicAdd(&deg[o], 1);
}

// ---------------- segment allocation: wave-scan + one atomic per wave; also builds rrows ----------------
__global__ __launch_bounds__(256)
void alloc_offs(const int* __restrict__ mlist, const int* __restrict__ mcount,
                const int* __restrict__ deg, int* __restrict__ offs,
                int* __restrict__ tcur, int* __restrict__ rrows, int Mpad) {
  int i = blockIdx.x * 256 + threadIdx.x;
  int lane = threadIdx.x & 63;
  int mc = *mcount;
  if (i < Mpad) rrows[i] = (i < mc) ? mlist[i] : 0;
  int o = (i < mc) ? mlist[i] : 0;
  int d = (i < mc) ? deg[o] : 0;
  int x = d;
#pragma unroll
  for (int s = 1; s < 64; s <<= 1) {
    int y = __shfl_up(x, s, 64);
    if (lane >= s) x += y;
  }
  int wt = __shfl(x, 63, 64);
  int base = 0;
  if (lane == 63 && wt > 0) base = atomicAdd(tcur, wt);
  base = __shfl(base, 63, 64);
  if (i < mc) offs[o] = base + (x - d);
}

__global__ void fill_edges(const int* __restrict__ obj_idx, const int* __restrict__ evt_idx,
                           const int* __restrict__ mask, const int* __restrict__ offs,
                           int* __restrict__ cursor, int* __restrict__ elist, int n) {
  int e = blockIdx.x * 256 + threadIdx.x;
  if (e >= n) return;
  int o = obj_idx[e];
  if (!mask[o]) return;
  int pos = atomicAdd(&cursor[o], 1);
  elist[offs[o] + pos] = evt_idx[e];
}

// ---------------- gather + cvt: objc[i] = bf16(objX[rrows[i]]) ----------------
__global__ __launch_bounds__(256)
void gather_cvt(const float* __restrict__ objX, const int* __restrict__ rrows,
                u16* __restrict__ objc, int Mpad) {
  int row = blockIdx.x * 4 + (threadIdx.x >> 6);
  int lane = threadIdx.x & 63;
  if (row >= Mpad) return;
  int src = rrows[row];
  float4 v = *(const float4*)(objX + (size_t)src * 256 + lane * 4);
  u16x4_t o;
  o.x = f2b(v.x); o.y = f2b(v.y); o.z = f2b(v.z); o.w = f2b(v.w);
  *(u16x4_t*)(objc + (size_t)row * 256 + lane * 4) = o;
}

// ---------------- register-accumulated scatter-mean, compacted output ----------------
__global__ __launch_bounds__(256)
void accum_prof(const u16* __restrict__ P, const int* __restrict__ elist,
                const int* __restrict__ offs, const int* __restrict__ deg,
                const int* __restrict__ mlist, const int* __restrict__ mcount,
                u16* __restrict__ prof, int Mpad) {
  const int wave = threadIdx.x >> 6;
  const int lane = threadIdx.x & 63;
  const int i = blockIdx.x * 4 + wave;
  if (i >= Mpad) return;
  const int mc = *mcount;
  float a0 = 0.f, a1 = 0.f, a2 = 0.f, a3 = 0.f;
  int d = 0;
  if (i < mc) {
    const int o = mlist[i];
    const int off = offs[o];
    d = deg[o];
    int j = 0;
    for (; j + 1 < d; j += 2) {
      int e0 = elist[off + j], e1 = elist[off + j + 1];
      u16x4_t p0 = *(const u16x4_t*)(P + (size_t)e0 * 256 + lane * 4);
      u16x4_t p1 = *(const u16x4_t*)(P + (size_t)e1 * 256 + lane * 4);
      a0 += b2f(p0.x) + b2f(p1.x);
      a1 += b2f(p0.y) + b2f(p1.y);
      a2 += b2f(p0.z) + b2f(p1.z);
      a3 += b2f(p0.w) + b2f(p1.w);
    }
    if (j < d) {
      int e0 = elist[off + j];
      u16x4_t p0 = *(const u16x4_t*)(P + (size_t)e0 * 256 + lane * 4);
      a0 += b2f(p0.x); a1 += b2f(p0.y); a2 += b2f(p0.z); a3 += b2f(p0.w);
    }
  }
  float s = 1.f / fmaxf((float)d, 1.f);
  u16x4_t ov;
  ov.x = f2b(a0 * s); ov.y = f2b(a1 * s); ov.z = f2b(a2 * s); ov.w = f2b(a3 * s);
  *(u16x4_t*)(prof + (size_t)i * 256 + lane * 4) = ov;
}

// ---------------- streaming MFMA GEMM (K=256, 128-col B panel in LDS) ----------------
// C[:, n0:n0+128] = A[M,256] @ B[n0:n0+128, 256]^T + bias. AF32: A fp32, packed in regs.
// B panel staged ONCE (XOR-swizzled chunks); waves stream 16-row A tiles with
// full-row register prefetch (16 KB/wave in flight) -> barrier-free main loop.
template<int RELU, int AF32>
__global__ __launch_bounds__(256, 2)
void gemm_stream(const u16* __restrict__ Ab, const float* __restrict__ Af,
                 const u16* __restrict__ B, const float* __restrict__ bias,
                 u16* __restrict__ C, int M, int N, int nIter, int rowStride) {
  __shared__ u16 lB[128 * 256];   // 64 KB
  const int tid  = threadIdx.x;
  const int lane = tid & 63;
  const int wave = tid >> 6;
  const int n0   = blockIdx.y * 128;
  const int la15 = lane & 15;
  const int kof8 = (lane >> 4) * 8;

  // stage B panel: 4096 x 16B segs; LDS chunk cp holds logical chunk (cp&24)|((cp^row)&7)
#pragma unroll
  for (int s = 0; s < 16; ++s) {
    int seg = s * 256 + tid;
    int row = seg >> 5;
    int cp  = seg & 31;
    int c   = (cp & 24) | ((cp ^ row) & 7);
    const u16* gB = B + (size_t)(n0 + row) * 256 + c * 8;
    __builtin_amdgcn_global_load_lds(
        (const __attribute__((address_space(1))) void*)gB,
        (__attribute__((address_space(3))) void*)(lB + s * 2048 + wave * 512),
        16, 0, 0);
  }
  __syncthreads();

  float4 va[8][2];   // AF32 prefetch (full 256B row segment per lane)
  bf16x8 vb[8];      // bf16 prefetch

  // prefetch row-tile 0
  {
    int rb = blockIdx.x * 64 + wave * 16;
    int ar = rb + la15; ar = (ar < M) ? ar : (M - 1);
    if (AF32) {
      const float* ap = Af + (size_t)ar * 256 + kof8;
#pragma unroll
      for (int ks = 0; ks < 8; ++ks) {
        va[ks][0] = *(const float4*)(ap + ks * 32);
        va[ks][1] = *(const float4*)(ap + ks * 32 + 4);
      }
    } else {
      const u16* ap = Ab + (size_t)ar * 256 + kof8;
#pragma unroll
      for (int ks = 0; ks < 8; ++ks) vb[ks] = *(const bf16x8*)(ap + ks * 32);
    }
  }

  const int crow = (lane >> 4) * 4;

  for (int t = 0; t < nIter; ++t) {
    const int rb = t * rowStride + blockIdx.x * 64 + wave * 16;

    // consume prefetch into cur
    bf16x8 cur[8];
    if (AF32) {
#pragma unroll
      for (int ks = 0; ks < 8; ++ks) cur[ks] = pack8(va[ks][0], va[ks][1]);
    } else {
#pragma unroll
      for (int ks = 0; ks < 8; ++ks) cur[ks] = vb[ks];
    }

    // issue prefetch for next row-tile (overlaps with compute below)
    if (t + 1 < nIter) {
      int rb2 = (t + 1) * rowStride + blockIdx.x * 64 + wave * 16;
      int ar = rb2 + la15; ar = (ar < M) ? ar : (M - 1);
      if (AF32) {
        const float* ap = Af + (size_t)ar * 256 + kof8;
#pragma unroll
        for (int ks = 0; ks < 8; ++ks) {
          va[ks][0] = *(const float4*)(ap + ks * 32);
          va[ks][1] = *(const float4*)(ap + ks * 32 + 4);
        }
      } else {
        const u16* ap = Ab + (size_t)ar * 256 + kof8;
#pragma unroll
        for (int ks = 0; ks < 8; ++ks) vb[ks] = *(const bf16x8*)(ap + ks * 32);
      }
    }

    // compute 16 x 128 tile
    f32x4 acc[8] = {};
#pragma unroll
    for (int ks = 0; ks < 8; ++ks) {
#pragma unroll
      for (int j = 0; j < 8; ++j) {
        int rj = j * 16 + la15;
        int c  = ks * 4 + (lane >> 4);
        int cp = (c & 24) | ((c ^ rj) & 7);
        bf16x8 bfr = *(const bf16x8*)(lB + rj * 256 + cp * 8);
        acc[j] = __builtin_amdgcn_mfma_f32_16x16x32_bf16(cur[ks], bfr, acc[j], 0, 0, 0);
      }
    }

    // epilogue: C/D layout col=lane&15, row=(lane>>4)*4+reg (verified m89/m91)
#pragma unroll
    for (int j = 0; j < 8; ++j) {
      int col = n0 + j * 16 + la15;
      float bv = bias[col];
#pragma unroll
      for (int q = 0; q < 4; ++q) {
        int row = rb + crow + q;
        if (row < M) {
          float v = acc[j][q] + bv;
          if (RELU) v = fmaxf(v, 0.f);
          C[(size_t)row * N + col] = f2b(v);
        }
      }
    }
  }
}

// ---------------- GRU gates + masked blend (float4-vectorized; 4 rows / block) ----------------
__global__ __launch_bounds__(256)
void gate_out(const u16* __restrict__ gi, const u16* __restrict__ gh,
              const float* __restrict__ objX, const int* __restrict__ mask,
              const int* __restrict__ cpos, float* __restrict__ out, int nObj) {
  const int wave = threadIdx.x >> 6;
  const int lane = threadIdx.x & 63;
  const int row = blockIdx.x * 4 + wave;
  if (row >= nObj) return;
  float4 x4 = *(const float4*)(objX + (size_t)row * 256 + lane * 4);
  float4 r4 = x4;
  if (mask[row]) {
    size_t b = (size_t)cpos[row] * 768 + lane * 4;
    u16x4_t ir = *(const u16x4_t*)(gi + b);
    u16x4_t iz = *(const u16x4_t*)(gi + b + 256);
    u16x4_t in_ = *(const u16x4_t*)(gi + b + 512);
    u16x4_t hr = *(const u16x4_t*)(gh + b);
    u16x4_t hz = *(const u16x4_t*)(gh + b + 256);
    u16x4_t hn = *(const u16x4_t*)(gh + b + 512);
    float xs[4] = {x4.x, x4.y, x4.z, x4.w};
    u16 irs[4] = {ir.x, ir.y, ir.z, ir.w};
    u16 izs[4] = {iz.x, iz.y, iz.z, iz.w};
    u16 ins[4] = {in_.x, in_.y, in_.z, in_.w};
    u16 hrs[4] = {hr.x, hr.y, hr.z, hr.w};
    u16 hzs[4] = {hz.x, hz.y, hz.z, hz.w};
    u16 hns[4] = {hn.x, hn.y, hn.z, hn.w};
    float rs[4];
#pragma unroll
    for (int q = 0; q < 4; ++q) {
      float r = 1.f / (1.f + __expf(-(b2f(irs[q]) + b2f(hrs[q]))));
      float z = 1.f / (1.f + __expf(-(b2f(izs[q]) + b2f(hzs[q]))));
      float a = b2f(ins[q]) + r * b2f(hns[q]);
      float n = 1.f - 2.f / (__expf(2.f * a) + 1.f);
      rs[q] = (1.f - z) * n + z * xs[q];
    }
    r4.x = rs[0]; r4.y = rs[1]; r4.z = rs[2]; r4.w = rs[3];
  }
  *(float4*)(out + (size_t)row * 256 + lane * 4) = r4;
}

// ---------------- workspace layout (bytes) ----------------
//           0  P      51,200,000  (dead after accum) -> gi reuse (38,535,168)
//  51,200,000  gh     38,535,168
//  89,735,168  prof   12,845,056  (25088 x 256 bf16 compact)
// 102,580,224  objc   12,845,056  (gathered objX rows, bf16)
// 115,425,280  wb        917,504  (wpb|wib|whb)
// 116,342,784  deg       200,000  \
// 116,542,784  cursor    200,000   |  one memset zeroes
// 116,742,784  mask      200,000   |  [116,342,784 .. 116,942,912)
// 116,942,784  mcount         64   |
// 116,942,848  tcur           64  /
// 116,942,912  cpos      200,000
// 117,142,912  offs      200,000
// 117,342,912  mlist     100,352
// 117,443,264  rrows     100,352
// 117,543,616  elist   2,000,000
// total 119,543,616

extern "C" void kernel_launch(void* const* d_in, const int* in_sizes, int n_in,
                              void* d_out, int out_size, void* d_ws, size_t ws_size,
                              hipStream_t stream) {
  const float* objX   = (const float*)d_in[0];
  const float* evtX   = (const float*)d_in[1];
  const int* obj_idx  = (const int*)d_in[2];
  const int* evt_idx  = (const int*)d_in[3];
  const int* main_idx = (const int*)d_in[4];
  const float* Wp = (const float*)d_in[5];
  const float* bp = (const float*)d_in[6];
  const float* Wi = (const float*)d_in[7];
  const float* bi = (const float*)d_in[8];
  const float* Wh = (const float*)d_in[9];
  const float* bh = (const float*)d_in[10];

  const int nObj  = in_sizes[0] / 256;   // 50000
  const int nEvt  = in_sizes[1] / 256;   // 100000
  const int nEdge = in_sizes[2];         // 500000
  const int nMain = in_sizes[4];         // 25000
  const int Mpad  = ((nMain + 127) / 128) * 128;  // 25088

  char* ws = (char*)d_ws;
  u16*   P     = (u16*)(ws + 0);
  u16*   gi    = (u16*)(ws + 0);
  u16*   gh    = (u16*)(ws + 51200000);
  u16*   prof  = (u16*)(ws + 89735168);
  u16*   objc  = (u16*)(ws + 102580224);
  u16*   wb    = (u16*)(ws + 115425280);
  u16*   wpb   = wb;
  u16*   wib   = wb + 65536;
  u16*   whb   = wb + 262144;
  int*   deg   = (int*)(ws + 116342784);
  int*   cursor= (int*)(ws + 116542784);
  int*   mask  = (int*)(ws + 116742784);
  int*   mcount= (int*)(ws + 116942784);
  int*   tcur  = (int*)(ws + 116942848);
  int*   cpos  = (int*)(ws + 116942912);
  int*   offs  = (int*)(ws + 117142912);
  int*   mlist = (int*)(ws + 117342912);
  int*   rrows = (int*)(ws + 117443264);
  int*   elist = (int*)(ws + 117543616);
  float* out   = (float*)d_out;

  // zero deg/cursor/mask/mcount/tcur in one shot
  hipMemsetAsync(ws + 116342784, 0, 600128, stream);

  init_misc<<<546, 256, 0, stream>>>(Wp, Wi, Wh, wb, main_idx, mask, mlist, cpos, mcount, nMain);

  // P = relu(evtX @ Wp^T + bp)  [100000 x 256]: grid 256x2 = 2 blocks/CU
  {
    const int gx = 256, rowStride = gx * 64;                 // 16384
    const int nIter = (nEvt + rowStride - 1) / rowStride;    // 7
    gemm_stream<1, 1><<<dim3(gx, 2), 256, 0, stream>>>(
        nullptr, evtX, wpb, bp, P, nEvt, 256, nIter, rowStride);
  }

  count_edges<<<(nEdge + 255) / 256, 256, 0, stream>>>(obj_idx, mask, deg, nEdge);
  alloc_offs<<<Mpad / 256, 256, 0, stream>>>(mlist, mcount, deg, offs, tcur, rrows, Mpad);
  fill_edges<<<(nEdge + 255) / 256, 256, 0, stream>>>(obj_idx, evt_idx, mask, offs, cursor, elist, nEdge);

  gather_cvt<<<(Mpad + 3) / 4, 256, 0, stream>>>(objX, rrows, objc, Mpad);

  accum_prof<<<(Mpad + 3) / 4, 256, 0, stream>>>(P, elist, offs, deg, mlist, mcount, prof, Mpad);

  // compact GRU GEMMs [25088 x 768]: grid 85x6 = 510 blocks ~ 2/CU
  {
    const int gx = 85, rowStride = gx * 64;                  // 5440
    const int nIter = (Mpad + rowStride - 1) / rowStride;    // 5
    gemm_stream<0, 0><<<dim3(gx, 6), 256, 0, stream>>>(
        prof, nullptr, wib, bi, gi, Mpad, 768, nIter, rowStride);
    gemm_stream<0, 0><<<dim3(gx, 6), 256, 0, stream>>>(
        objc, nullptr, whb, bh, gh, Mpad, 768, nIter, rowStride);
  }

  gate_out<<<(nObj + 3) / 4, 256, 0, stream>>>(gi, gh, objX, mask, cpos, out, nObj);
}

// Round 6
// 377.451 us; speedup vs baseline: 1.4829x; 1.4829x over previous
//
#include <hip/hip_runtime.h>

typedef unsigned short u16;
typedef __attribute__((ext_vector_type(8))) short bf16x8;
typedef __attribute__((ext_vector_type(4))) float f32x4;

struct __align__(8) u16x4_t { u16 x, y, z, w; };

__device__ __forceinline__ float b2f(u16 b) {
  union { unsigned u; float f; } v; v.u = ((unsigned)b) << 16; return v.f;
}
__device__ __forceinline__ u16 f2b(float f) {
  union { float f; unsigned u; } v; v.f = f;
  unsigned r = v.u + 0x7fffu + ((v.u >> 16) & 1u);
  return (u16)(r >> 16);
}

// ---------------- prep: evtX cvt + weight cvt + mask/mlist build, one dispatch ----------------
__global__ void prep(const float* __restrict__ evtX, u16* __restrict__ evtb, int nEvtF4,
                     const float* __restrict__ Wp, const float* __restrict__ Wi,
                     const float* __restrict__ Wh, u16* __restrict__ wb,
                     const int* __restrict__ main_idx, int* __restrict__ mask,
                     int* __restrict__ mlist, int* __restrict__ cpos,
                     int* __restrict__ mcount, int nMain) {
  const int cvtBlocks = nEvtF4 / 256;           // 25000
  int b = blockIdx.x;
  if (b < cvtBlocks) {
    int t = b * 256 + threadIdx.x;
    float4 v = ((const float4*)evtX)[t];
    u16x4_t o;
    o.x = f2b(v.x); o.y = f2b(v.y); o.z = f2b(v.z); o.w = f2b(v.w);
    ((u16x4_t*)evtb)[t] = o;
  } else if (b < cvtBlocks + 448) {
    int t = (b - cvtBlocks) * 256 + threadIdx.x;  // [0, 114688)
    const float* src; int o;
    if (t < 16384)      { src = Wp; o = t; }
    else if (t < 65536) { src = Wi; o = t - 16384; }
    else                { src = Wh; o = t - 65536; }
    float4 v = ((const float4*)src)[o];
    u16x4_t q;
    q.x = f2b(v.x); q.y = f2b(v.y); q.z = f2b(v.z); q.w = f2b(v.w);
    ((u16x4_t*)wb)[t] = q;
  } else {
    int t = (b - cvtBlocks - 448) * 256 + threadIdx.x;
    if (t < nMain) {
      int o = main_idx[t];
      if (atomicCAS(&mask[o], 0, 1) == 0) {
        int i = atomicAdd(mcount, 1);
        mlist[i] = o;
        cpos[o] = i;
      }
    }
  }
}

// ---------------- masked degree count ----------------
__global__ void count_edges(const int* __restrict__ obj_idx, const int* __restrict__ mask,
                            int* __restrict__ deg, int n) {
  int e = blockIdx.x * 256 + threadIdx.x;
  if (e >= n) return;
  int o = obj_idx[e];
  if (mask[o]) atomicAdd(&deg[o], 1);
}

// ---------------- segment allocation: wave-scan + one atomic per wave; also builds rrows ----------------
__global__ __launch_bounds__(256)
void alloc_offs(const int* __restrict__ mlist, const int* __restrict__ mcount,
                const int* __restrict__ deg, int* __restrict__ offs,
                int* __restrict__ tcur, int* __restrict__ rrows, int Mpad) {
  int i = blockIdx.x * 256 + threadIdx.x;
  int lane = threadIdx.x & 63;
  int mc = *mcount;
  if (i < Mpad) rrows[i] = (i < mc) ? mlist[i] : 0;
  int o = (i < mc) ? mlist[i] : 0;
  int d = (i < mc) ? deg[o] : 0;
  int x = d;
#pragma unroll
  for (int s = 1; s < 64; s <<= 1) {
    int y = __shfl_up(x, s, 64);
    if (lane >= s) x += y;
  }
  int wt = __shfl(x, 63, 64);
  int base = 0;
  if (lane == 63 && wt > 0) base = atomicAdd(tcur, wt);
  base = __shfl(base, 63, 64);
  if (i < mc) offs[o] = base + (x - d);
}

__global__ void fill_edges(const int* __restrict__ obj_idx, const int* __restrict__ evt_idx,
                           const int* __restrict__ mask, const int* __restrict__ offs,
                           int* __restrict__ cursor, int* __restrict__ elist, int n) {
  int e = blockIdx.x * 256 + threadIdx.x;
  if (e >= n) return;
  int o = obj_idx[e];
  if (!mask[o]) return;
  int pos = atomicAdd(&cursor[o], 1);
  elist[offs[o] + pos] = evt_idx[e];
}

// ---------------- fused: profile scatter-mean accumulation + objX gather/cvt ----------------
// wave handles compact row i: (a) gather objX[rrows[i]] -> objc[i] bf16,
// (b) register-accumulate mean of P rows -> prof[i]. Independent work, overlapped.
__global__ __launch_bounds__(256)
void accum_gather(const u16* __restrict__ P, const int* __restrict__ elist,
                  const int* __restrict__ offs, const int* __restrict__ deg,
                  const int* __restrict__ mlist, const int* __restrict__ mcount,
                  const float* __restrict__ objX, const int* __restrict__ rrows,
                  u16* __restrict__ prof, u16* __restrict__ objc, int Mpad) {
  const int wave = threadIdx.x >> 6;
  const int lane = threadIdx.x & 63;
  const int i = blockIdx.x * 4 + wave;
  if (i >= Mpad) return;

  // gather objX row (issue loads early; independent of accum below)
  int src = rrows[i];
  float4 xv = *(const float4*)(objX + (size_t)src * 256 + lane * 4);

  const int mc = *mcount;
  float a0 = 0.f, a1 = 0.f, a2 = 0.f, a3 = 0.f;
  int d = 0;
  if (i < mc) {
    const int o = mlist[i];
    const int off = offs[o];
    d = deg[o];
    int j = 0;
    for (; j + 1 < d; j += 2) {
      int e0 = elist[off + j], e1 = elist[off + j + 1];
      u16x4_t p0 = *(const u16x4_t*)(P + (size_t)e0 * 256 + lane * 4);
      u16x4_t p1 = *(const u16x4_t*)(P + (size_t)e1 * 256 + lane * 4);
      a0 += b2f(p0.x) + b2f(p1.x);
      a1 += b2f(p0.y) + b2f(p1.y);
      a2 += b2f(p0.z) + b2f(p1.z);
      a3 += b2f(p0.w) + b2f(p1.w);
    }
    if (j < d) {
      int e0 = elist[off + j];
      u16x4_t p0 = *(const u16x4_t*)(P + (size_t)e0 * 256 + lane * 4);
      a0 += b2f(p0.x); a1 += b2f(p0.y); a2 += b2f(p0.z); a3 += b2f(p0.w);
    }
  }
  float s = 1.f / fmaxf((float)d, 1.f);
  u16x4_t pv;
  pv.x = f2b(a0 * s); pv.y = f2b(a1 * s); pv.z = f2b(a2 * s); pv.w = f2b(a3 * s);
  *(u16x4_t*)(prof + (size_t)i * 256 + lane * 4) = pv;

  u16x4_t ov;
  ov.x = f2b(xv.x); ov.y = f2b(xv.y); ov.z = f2b(xv.z); ov.w = f2b(xv.w);
  *(u16x4_t*)(objc + (size_t)i * 256 + lane * 4) = ov;
}

// ---------------- R2-proven MFMA GEMM core: C[:,n0:n0+128] tile, K=256 ----------------
// 128x128 tile, BK=64, global_load_lds width=16 both operands, 4 waves x 64x64.
template<int RELU>
__device__ __forceinline__
void gemm_core(const u16* __restrict__ A, const u16* __restrict__ B,
               const float* __restrict__ bias, u16* __restrict__ C,
               int M, int N, int n0, u16* lA, u16* lB) {
  const int tid  = threadIdx.x;
  const int lane = tid & 63;
  const int wave = tid >> 6;
  const int m0 = blockIdx.x * 128;
  const int mR = (wave & 1) * 64;
  const int nC = (wave >> 1) * 64;

  f32x4 acc[4][4] = {};

  for (int kt = 0; kt < 256; kt += 64) {
    __syncthreads();  // protect LDS from previous iteration's readers
#pragma unroll
    for (int s = 0; s < 4; ++s) {
      int slot = s * 256 + tid;
      int row  = slot >> 3;
      int kk   = (slot & 7) * 8;
      int ar = m0 + row; ar = (ar < M) ? ar : (M - 1);
      const u16* gA = A + (size_t)ar * 256 + (kt + kk);
      __builtin_amdgcn_global_load_lds(
          (const __attribute__((address_space(1))) void*)gA,
          (__attribute__((address_space(3))) void*)(lA + s * 2048 + wave * 512),
          16, 0, 0);
      const u16* gB = B + (size_t)(n0 + row) * 256 + (kt + kk);
      __builtin_amdgcn_global_load_lds(
          (const __attribute__((address_space(1))) void*)gB,
          (__attribute__((address_space(3))) void*)(lB + s * 2048 + wave * 512),
          16, 0, 0);
    }
    __syncthreads();  // drains vmcnt before LDS reads

#pragma unroll
    for (int ks = 0; ks < 2; ++ks) {
      const int kb = ks * 32 + (lane >> 4) * 8;
      bf16x8 af[4], bfr[4];
#pragma unroll
      for (int i = 0; i < 4; ++i) {
        af[i]  = *(const bf16x8*)(lA + (mR + i * 16 + (lane & 15)) * 64 + kb);
        bfr[i] = *(const bf16x8*)(lB + (nC + i * 16 + (lane & 15)) * 64 + kb);
      }
#pragma unroll
      for (int i = 0; i < 4; ++i)
#pragma unroll
        for (int j = 0; j < 4; ++j)
          acc[i][j] = __builtin_amdgcn_mfma_f32_16x16x32_bf16(af[i], bfr[j], acc[i][j], 0, 0, 0);
    }
  }

  // C/D layout: col=lane&15, row=(lane>>4)*4+reg (verified m89/m91)
  const int crow = (lane >> 4) * 4;
  const int ccol = lane & 15;
#pragma unroll
  for (int i = 0; i < 4; ++i) {
#pragma unroll
    for (int j = 0; j < 4; ++j) {
      int col = n0 + nC + j * 16 + ccol;
      float bv = bias[col];
#pragma unroll
      for (int q = 0; q < 4; ++q) {
        int row = m0 + mR + i * 16 + crow + q;
        if (row < M) {
          float v = acc[i][j][q] + bv;
          if (RELU) v = fmaxf(v, 0.f);
          C[(size_t)row * N + col] = f2b(v);
        }
      }
    }
  }
}

__global__ __launch_bounds__(256, 2)
void gemm_p(const u16* __restrict__ A, const u16* __restrict__ B,
            const float* __restrict__ bias, u16* __restrict__ C, int M) {
  __shared__ u16 lA[128 * 64];
  __shared__ u16 lB[128 * 64];
  gemm_core<1>(A, B, bias, C, M, 256, blockIdx.y * 128, lA, lB);
}

// both GRU GEMMs in one dispatch: y in [0,6) -> gi, [6,12) -> gh
__global__ __launch_bounds__(256, 2)
void gemm2_dual(const u16* __restrict__ prof, const u16* __restrict__ objc,
                const u16* __restrict__ wib, const u16* __restrict__ whb,
                const float* __restrict__ bi, const float* __restrict__ bh,
                u16* __restrict__ gi, u16* __restrict__ gh, int Mpad) {
  __shared__ u16 lA[128 * 64];
  __shared__ u16 lB[128 * 64];
  int y = blockIdx.y;
  if (y < 6) gemm_core<0>(prof, wib, bi, gi, Mpad, 768, y * 128, lA, lB);
  else       gemm_core<0>(objc, whb, bh, gh, Mpad, 768, (y - 6) * 128, lA, lB);
}

// ---------------- GRU gates + masked blend (float4-vectorized; 4 rows / block) ----------------
__global__ __launch_bounds__(256)
void gate_out(const u16* __restrict__ gi, const u16* __restrict__ gh,
              const float* __restrict__ objX, const int* __restrict__ mask,
              const int* __restrict__ cpos, float* __restrict__ out, int nObj) {
  const int wave = threadIdx.x >> 6;
  const int lane = threadIdx.x & 63;
  const int row = blockIdx.x * 4 + wave;
  if (row >= nObj) return;
  float4 x4 = *(const float4*)(objX + (size_t)row * 256 + lane * 4);
  float4 r4 = x4;
  if (mask[row]) {
    size_t b = (size_t)cpos[row] * 768 + lane * 4;
    u16x4_t ir = *(const u16x4_t*)(gi + b);
    u16x4_t iz = *(const u16x4_t*)(gi + b + 256);
    u16x4_t in_ = *(const u16x4_t*)(gi + b + 512);
    u16x4_t hr = *(const u16x4_t*)(gh + b);
    u16x4_t hz = *(const u16x4_t*)(gh + b + 256);
    u16x4_t hn = *(const u16x4_t*)(gh + b + 512);
    float xs[4] = {x4.x, x4.y, x4.z, x4.w};
    u16 irs[4] = {ir.x, ir.y, ir.z, ir.w};
    u16 izs[4] = {iz.x, iz.y, iz.z, iz.w};
    u16 ins[4] = {in_.x, in_.y, in_.z, in_.w};
    u16 hrs[4] = {hr.x, hr.y, hr.z, hr.w};
    u16 hzs[4] = {hz.x, hz.y, hz.z, hz.w};
    u16 hns[4] = {hn.x, hn.y, hn.z, hn.w};
    float rs[4];
#pragma unroll
    for (int q = 0; q < 4; ++q) {
      float r = 1.f / (1.f + __expf(-(b2f(irs[q]) + b2f(hrs[q]))));
      float z = 1.f / (1.f + __expf(-(b2f(izs[q]) + b2f(hzs[q]))));
      float a = b2f(ins[q]) + r * b2f(hns[q]);
      float n = 1.f - 2.f / (__expf(2.f * a) + 1.f);
      rs[q] = (1.f - z) * n + z * xs[q];
    }
    r4.x = rs[0]; r4.y = rs[1]; r4.z = rs[2]; r4.w = rs[3];
  }
  *(float4*)(out + (size_t)row * 256 + lane * 4) = r4;
}

// ---------------- workspace layout (bytes) ----------------
//           0  P      51,200,000  (dead after accum_gather) -> gi reuse
//  51,200,000  gh     38,535,168
//  89,735,168  prof   12,845,056
// 102,580,224  objc   12,845,056
// 115,425,280  evtb   51,200,000  (dead after gemm_p)
// 166,625,280  wb        917,504  (wpb|wib|whb)
// 167,542,784  deg       200,000  \
// 167,742,784  cursor    200,000   |  one memset zeroes
// 167,942,784  mask      200,000   |  [167,542,784 .. 168,142,912)
// 168,142,784  mcount         64   |
// 168,142,848  tcur           64  /
// 168,142,912  cpos      200,000
// 168,342,912  offs      200,000
// 168,542,912  mlist     100,352
// 168,643,264  rrows     100,352
// 168,743,616  elist   2,000,000
// total 170,743,616

extern "C" void kernel_launch(void* const* d_in, const int* in_sizes, int n_in,
                              void* d_out, int out_size, void* d_ws, size_t ws_size,
                              hipStream_t stream) {
  const float* objX   = (const float*)d_in[0];
  const float* evtX   = (const float*)d_in[1];
  const int* obj_idx  = (const int*)d_in[2];
  const int* evt_idx  = (const int*)d_in[3];
  const int* main_idx = (const int*)d_in[4];
  const float* Wp = (const float*)d_in[5];
  const float* bp = (const float*)d_in[6];
  const float* Wi = (const float*)d_in[7];
  const float* bi = (const float*)d_in[8];
  const float* Wh = (const float*)d_in[9];
  const float* bh = (const float*)d_in[10];

  const int nObj  = in_sizes[0] / 256;   // 50000
  const int nEvt  = in_sizes[1] / 256;   // 100000
  const int nEdge = in_sizes[2];         // 500000
  const int nMain = in_sizes[4];         // 25000
  const int Mpad  = ((nMain + 127) / 128) * 128;  // 25088

  char* ws = (char*)d_ws;
  u16*   P     = (u16*)(ws + 0);
  u16*   gi    = (u16*)(ws + 0);
  u16*   gh    = (u16*)(ws + 51200000);
  u16*   prof  = (u16*)(ws + 89735168);
  u16*   objc  = (u16*)(ws + 102580224);
  u16*   evtb  = (u16*)(ws + 115425280);
  u16*   wb    = (u16*)(ws + 166625280);
  u16*   wpb   = wb;
  u16*   wib   = wb + 65536;
  u16*   whb   = wb + 262144;
  int*   deg   = (int*)(ws + 167542784);
  int*   cursor= (int*)(ws + 167742784);
  int*   mask  = (int*)(ws + 167942784);
  int*   mcount= (int*)(ws + 168142784);
  int*   tcur  = (int*)(ws + 168142848);
  int*   cpos  = (int*)(ws + 168142912);
  int*   offs  = (int*)(ws + 168342912);
  int*   mlist = (int*)(ws + 168542912);
  int*   rrows = (int*)(ws + 168643264);
  int*   elist = (int*)(ws + 168743616);
  float* out   = (float*)d_out;

  hipMemsetAsync(ws + 167542784, 0, 600128, stream);

  const int nEvtF4 = in_sizes[1] / 4;                       // 6,400,000
  const int prepGrid = nEvtF4 / 256 + 448 + (nMain + 255) / 256;  // 25546
  prep<<<prepGrid, 256, 0, stream>>>(evtX, evtb, nEvtF4, Wp, Wi, Wh, wb,
                                     main_idx, mask, mlist, cpos, mcount, nMain);

  // P = relu(evtb @ Wp^T + bp)  [100000 x 256]
  gemm_p<<<dim3((nEvt + 127) / 128, 2), 256, 0, stream>>>(evtb, wpb, bp, P, nEvt);

  count_edges<<<(nEdge + 255) / 256, 256, 0, stream>>>(obj_idx, mask, deg, nEdge);
  alloc_offs<<<Mpad / 256, 256, 0, stream>>>(mlist, mcount, deg, offs, tcur, rrows, Mpad);
  fill_edges<<<(nEdge + 255) / 256, 256, 0, stream>>>(obj_idx, evt_idx, mask, offs, cursor, elist, nEdge);

  accum_gather<<<(Mpad + 3) / 4, 256, 0, stream>>>(P, elist, offs, deg, mlist, mcount,
                                                   objX, rrows, prof, objc, Mpad);

  // gi = prof @ Wi^T + bi ; gh = objc @ Wh^T + bh  [25088 x 768], one dispatch
  gemm2_dual<<<dim3(Mpad / 128, 12), 256, 0, stream>>>(prof, objc, wib, whb, bi, bh, gi, gh, Mpad);

  gate_out<<<(nObj + 3) / 4, 256, 0, stream>>>(gi, gh, objX, mask, cpos, out, nObj);
}